// Round 14
// baseline (1383.959 us; speedup 1.0000x reference)
//
#include <hip/hip_runtime.h>
#include <hip/hip_fp16.h>

#define NN 50000
#define NE 800000
#define CIN 128
#define HH 64
#define NCLS 40
#define NL 15
#define DTC 0.1f
#define LNEPS 1e-5f
#define NB_SCAN 196   // ceil(50000/256)

typedef float f32x2 __attribute__((ext_vector_type(2)));

// ---------------- bf16x2 / fp16x2 / fp8x2 pack-unpack ----------------

__device__ inline unsigned pack_bf2(float x, float y) {
    unsigned ux = __float_as_uint(x);
    unsigned uy = __float_as_uint(y);
    ux = (ux + 0x7fffu + ((ux >> 16) & 1u)) >> 16;   // RNE
    uy = (uy + 0x7fffu + ((uy >> 16) & 1u)) >> 16;
    return ux | (uy << 16);
}
__device__ inline float2 unpack_bf2(unsigned p) {
    float2 r;
    r.x = __uint_as_float(p << 16);
    r.y = __uint_as_float(p & 0xffff0000u);
    return r;
}
__device__ inline unsigned pack_h2(float x, float y) {
    __half2 h = __floats2half2_rn(x, y);
    return *reinterpret_cast<unsigned*>(&h);
}
__device__ inline float2 unpack_h2(unsigned p) {
    __half2 h = *reinterpret_cast<__half2*>(&p);
    return __half22float2(h);
}
__device__ inline unsigned short pack_fp8x2(float x, float y) {
    int r = __builtin_amdgcn_cvt_pk_fp8_f32(x, y, 0, false);
    return (unsigned short)(r & 0xffff);
}
__device__ inline float2 unpack_fp8x2(unsigned short p) {
    f32x2 v = __builtin_amdgcn_cvt_pk_f32_fp8((int)(unsigned)p, false);
    float2 r; r.x = v.x; r.y = v.y; return r;
}

// ---------------- degree / normalization precompute ----------------

__global__ __launch_bounds__(256) void k_deg(const int* __restrict__ dst, int* __restrict__ deg) {
    int e = blockIdx.x * 256 + threadIdx.x;
    if (e < NE) atomicAdd(&deg[dst[e]], 1);
}

__global__ __launch_bounds__(256) void k_scan1(const int* __restrict__ deg, int* __restrict__ rp,
                                               int* __restrict__ bsum, float* __restrict__ dinv) {
    int i = blockIdx.x * 256 + threadIdx.x;
    int v = (i < NN) ? deg[i] : 0;
    if (i < NN) dinv[i] = rsqrtf(fmaxf((float)v, 1.0f));
    int lane = threadIdx.x & 63, wid = threadIdx.x >> 6;
    int inc = v;
#pragma unroll
    for (int d = 1; d < 64; d <<= 1) {
        int t = __shfl_up(inc, d, 64);
        if (lane >= d) inc += t;
    }
    __shared__ int wsum[4];
    if (lane == 63) wsum[wid] = inc;
    __syncthreads();
    int woff = 0;
#pragma unroll
    for (int w = 0; w < 4; ++w)
        if (w < wid) woff += wsum[w];
    if (i < NN) rp[i] = woff + inc - v;
    if (threadIdx.x == 255) bsum[blockIdx.x] = woff + inc;
}

__global__ __launch_bounds__(256) void k_scan2(const int* __restrict__ bsum, int* __restrict__ boff) {
    int t = threadIdx.x;
    int v = (t < NB_SCAN) ? bsum[t] : 0;
    int lane = t & 63, wid = t >> 6;
    int inc = v;
#pragma unroll
    for (int d = 1; d < 64; d <<= 1) {
        int tt = __shfl_up(inc, d, 64);
        if (lane >= d) inc += tt;
    }
    __shared__ int wsum[4];
    if (lane == 63) wsum[wid] = inc;
    __syncthreads();
    int woff = 0;
#pragma unroll
    for (int w = 0; w < 4; ++w)
        if (w < wid) woff += wsum[w];
    boff[t] = woff + inc - v;
}

__global__ __launch_bounds__(256) void k_scan3(int* __restrict__ rp, const int* __restrict__ boff) {
    int i = blockIdx.x * 256 + threadIdx.x;
    if (i < NN) rp[i] += boff[i >> 8];
    else if (i == NN) rp[NN] = NE;
}

// edge record: {src*128 byte-offset into fp8 row buffers, ewt bits} -> one 8B store
__global__ __launch_bounds__(256) void k_scatter(const int* __restrict__ src, const int* __restrict__ dst,
                                                 const float* __restrict__ dinv, const int* __restrict__ rp,
                                                 int* __restrict__ cnt, uint2* __restrict__ edges) {
    int e = blockIdx.x * 256 + threadIdx.x;
    if (e >= NE) return;
    int s = src[e], d = dst[e];
    int pos = rp[d] + atomicAdd(&cnt[d], 1);
    uint2 rec;
    rec.x = (unsigned)s * 128u;           // byte offset of row s (64 ch * 2B)
    rec.y = __float_as_uint(dinv[s] * dinv[d]);
    edges[pos] = rec;
}

// ---------------- lift: h = [tanh(x @ lift_w^T + b), ones]; packed h + layer-0 z0 ----

#define LIFT_NPB 16

__global__ __launch_bounds__(256) void k_lift(const float* __restrict__ x, const float* __restrict__ lw,
                                              const float* __restrict__ lb,
                                              const float* __restrict__ alpha, const float* __restrict__ beta,
                                              const float* __restrict__ dxp, const float* __restrict__ dyp,
                                              unsigned* __restrict__ hpk, unsigned short* __restrict__ z0bf8) {
    __shared__ unsigned Wt2[CIN / 2][HH + 1];
    __shared__ float xs[LIFT_NPB][CIN];
    int t = threadIdx.x;
    for (int idx = t; idx < (CIN / 2) * HH; idx += 256) {
        int c = idx & 63, kk = idx >> 6;
        Wt2[kk][c] = pack_bf2(lw[c * CIN + 2 * kk], lw[c * CIN + 2 * kk + 1]);
    }
    int n0 = blockIdx.x * LIFT_NPB;
#pragma unroll
    for (int i = 0; i < LIFT_NPB * CIN / 256; ++i) {
        int idx = i * 256 + t;
        int r = idx >> 7, c = idx & 127;
        xs[r][c] = x[(size_t)(n0 + r) * CIN + c];
    }
    __syncthreads();
    int lane = t & 63, wid = t >> 6;
    float bias = lb[lane];
    float a = alpha[0], b = beta[0];
    float idx0 = 1.0f / (1.0f + DTC * dxp[0]);
    float idy0 = 1.0f / (1.0f + DTC * dyp[0]);
    const float2* x0 = (const float2*)&xs[wid * 4 + 0][0];
    const float2* x1 = (const float2*)&xs[wid * 4 + 1][0];
    const float2* x2 = (const float2*)&xs[wid * 4 + 2][0];
    const float2* x3 = (const float2*)&xs[wid * 4 + 3][0];
    float ac0 = 0.f, ac1 = 0.f, ac2 = 0.f, ac3 = 0.f;
#pragma unroll 8
    for (int kk = 0; kk < CIN / 2; ++kk) {
        float2 wv = unpack_bf2(Wt2[kk][lane]);
        float2 v0 = x0[kk], v1 = x1[kk], v2 = x2[kk], v3 = x3[kk];
        ac0 = fmaf(v0.y, wv.y, fmaf(v0.x, wv.x, ac0));
        ac1 = fmaf(v1.y, wv.y, fmaf(v1.x, wv.x, ac1));
        ac2 = fmaf(v2.y, wv.y, fmaf(v2.x, wv.x, ac2));
        ac3 = fmaf(v3.y, wv.y, fmaf(v3.x, wv.x, ac3));
    }
#pragma unroll
    for (int i = 0; i < 4; ++i) {
        float acc = i == 0 ? ac0 : i == 1 ? ac1 : i == 2 ? ac2 : ac3;
        float hx = tanhf(bias + acc);
        int n = n0 + wid * 4 + i;
        hpk[(size_t)n * HH + lane] = pack_h2(hx, 1.0f);
        float rx = hx + DTC * (a * hx - b * hx);
        float ry = 1.0f + DTC * (b * hx - a);
        z0bf8[(size_t)n * HH + lane] = pack_fp8x2(rx * idx0, ry * idy0);
    }
}

// ---------------- phase1: channel-split half-row passes ----------------
// pass p gathers only bytes [64p, 64p+64) of each z0 row: per-pass operand is
// 3.2 MB -> fits each XCD's 4 MB L2 -> lower gather latency. One wave per node;
// lanes 0-31 process even edges, lanes 32-63 odd edges (2 edges / VMEM instr);
// halves combined by shfl_xor(32).

__device__ __forceinline__ void p1_cons(unsigned short g, float w, float& aX, float& aY) {
    float2 v = unpack_fp8x2(g);
    aX = fmaf(w, v.x, aX);
    aY = fmaf(w, v.y, aY);
}

__global__ __launch_bounds__(256) void k_phase1h(const unsigned short* __restrict__ z0bf8,
                                                 unsigned short* __restrict__ z1bf8,
                                                 const int* __restrict__ rp, const uint2* __restrict__ edges,
                                                 const float* __restrict__ dxp, const float* __restrict__ dyp,
                                                 int l, int pass) {
    int lane = threadIdx.x & 63, wid = threadIdx.x >> 6;
    int n = blockIdx.x * 4 + wid;            // grid = NN/4 = 12500
    bool hi = (lane >> 5) != 0;
    int lh = lane & 31;
    float dx = dxp[l], dy = dyp[l];
    float cx = DTC * dx / (1.0f + DTC * dx);
    float cy = DTC * dy / (1.0f + DTC * dy);
    int e0 = __builtin_amdgcn_readfirstlane(rp[n]);
    int e1 = __builtin_amdgcn_readfirstlane(rp[n + 1]);
    const char* base = (const char*)z0bf8 + pass * 64;
    int choff = lh * 2;
    float aX = 0.f, aY = 0.f;
    int e = e0;
    for (; e + 16 <= e1; e += 16) {
        uint4 q0 = *(const uint4*)(edges + e);
        uint4 q1 = *(const uint4*)(edges + e + 2);
        uint4 q2 = *(const uint4*)(edges + e + 4);
        uint4 q3 = *(const uint4*)(edges + e + 6);
        uint4 q4 = *(const uint4*)(edges + e + 8);
        uint4 q5 = *(const uint4*)(edges + e + 10);
        uint4 q6 = *(const uint4*)(edges + e + 12);
        uint4 q7 = *(const uint4*)(edges + e + 14);
        unsigned o0 = hi ? q0.z : q0.x, o1 = hi ? q1.z : q1.x;
        unsigned o2 = hi ? q2.z : q2.x, o3 = hi ? q3.z : q3.x;
        unsigned o4 = hi ? q4.z : q4.x, o5 = hi ? q5.z : q5.x;
        unsigned o6 = hi ? q6.z : q6.x, o7 = hi ? q7.z : q7.x;
        unsigned short g0 = *(const unsigned short*)(base + o0 + choff);
        unsigned short g1 = *(const unsigned short*)(base + o1 + choff);
        unsigned short g2 = *(const unsigned short*)(base + o2 + choff);
        unsigned short g3 = *(const unsigned short*)(base + o3 + choff);
        unsigned short g4 = *(const unsigned short*)(base + o4 + choff);
        unsigned short g5 = *(const unsigned short*)(base + o5 + choff);
        unsigned short g6 = *(const unsigned short*)(base + o6 + choff);
        unsigned short g7 = *(const unsigned short*)(base + o7 + choff);
        p1_cons(g0, __uint_as_float(hi ? q0.w : q0.y), aX, aY);
        p1_cons(g1, __uint_as_float(hi ? q1.w : q1.y), aX, aY);
        p1_cons(g2, __uint_as_float(hi ? q2.w : q2.y), aX, aY);
        p1_cons(g3, __uint_as_float(hi ? q3.w : q3.y), aX, aY);
        p1_cons(g4, __uint_as_float(hi ? q4.w : q4.y), aX, aY);
        p1_cons(g5, __uint_as_float(hi ? q5.w : q5.y), aX, aY);
        p1_cons(g6, __uint_as_float(hi ? q6.w : q6.y), aX, aY);
        p1_cons(g7, __uint_as_float(hi ? q7.w : q7.y), aX, aY);
    }
    for (; e < e1; e += 2) {
        uint2 rA = edges[e];
        bool vB = (e + 1 < e1);
        uint2 rB = vB ? edges[e + 1] : rA;
        unsigned wBbits = vB ? rB.y : 0u;
        unsigned off = hi ? rB.x : rA.x;
        float w = __uint_as_float(hi ? wBbits : rA.y);
        unsigned short g = *(const unsigned short*)(base + off + choff);
        p1_cons(g, w, aX, aY);
    }
    aX += __shfl_xor(aX, 32, 64);
    aY += __shfl_xor(aY, 32, 64);
    if (!hi) {
        size_t idx = (size_t)n * HH + pass * 32 + lh;
        float2 z0 = unpack_fp8x2(z0bf8[idx]);
        z1bf8[idx] = pack_fp8x2(fmaf(cx, aX, z0.x), fmaf(cy, aY, z0.y));
    }
}

// ---------------- phase2 gather core (unchanged from R13) ----------------

#define GLOAD(g, q, comp) unsigned short g = *(const unsigned short*)(base + q.comp + lane2)
#define CONS(g, q, wcomp, aX, aY)                                      \
    do {                                                               \
        float2 v = unpack_fp8x2(g);                                    \
        float w = __uint_as_float(q.wcomp);                            \
        aX = fmaf(w, v.x, aX);                                         \
        aY = fmaf(w, v.y, aY);                                         \
    } while (0)

__device__ __forceinline__ void batchAB(const char* __restrict__ base, const uint2* __restrict__ edges,
                                        int eA, int eB, int lane2,
                                        float& aXA, float& aYA, float& aXB, float& aYB) {
    uint4 qa0 = *(const uint4*)(edges + eA);
    uint4 qa1 = *(const uint4*)(edges + eA + 2);
    uint4 qa2 = *(const uint4*)(edges + eA + 4);
    uint4 qa3 = *(const uint4*)(edges + eA + 6);
    uint4 qb0 = *(const uint4*)(edges + eB);
    uint4 qb1 = *(const uint4*)(edges + eB + 2);
    uint4 qb2 = *(const uint4*)(edges + eB + 4);
    uint4 qb3 = *(const uint4*)(edges + eB + 6);
    GLOAD(ga0, qa0, x); GLOAD(ga1, qa0, z);
    GLOAD(ga2, qa1, x); GLOAD(ga3, qa1, z);
    GLOAD(ga4, qa2, x); GLOAD(ga5, qa2, z);
    GLOAD(ga6, qa3, x); GLOAD(ga7, qa3, z);
    GLOAD(gb0, qb0, x); GLOAD(gb1, qb0, z);
    GLOAD(gb2, qb1, x); GLOAD(gb3, qb1, z);
    GLOAD(gb4, qb2, x); GLOAD(gb5, qb2, z);
    GLOAD(gb6, qb3, x); GLOAD(gb7, qb3, z);
    CONS(ga0, qa0, y, aXA, aYA); CONS(ga1, qa0, w, aXA, aYA);
    CONS(ga2, qa1, y, aXA, aYA); CONS(ga3, qa1, w, aXA, aYA);
    CONS(ga4, qa2, y, aXA, aYA); CONS(ga5, qa2, w, aXA, aYA);
    CONS(ga6, qa3, y, aXA, aYA); CONS(ga7, qa3, w, aXA, aYA);
    CONS(gb0, qb0, y, aXB, aYB); CONS(gb1, qb0, w, aXB, aYB);
    CONS(gb2, qb1, y, aXB, aYB); CONS(gb3, qb1, w, aXB, aYB);
    CONS(gb4, qb2, y, aXB, aYB); CONS(gb5, qb2, w, aXB, aYB);
    CONS(gb6, qb3, y, aXB, aYB); CONS(gb7, qb3, w, aXB, aYB);
}

__device__ __forceinline__ void batch8(const char* __restrict__ base, const uint2* __restrict__ edges,
                                       int e, int lane2, float& accX, float& accY) {
    uint4 q0 = *(const uint4*)(edges + e);
    uint4 q1 = *(const uint4*)(edges + e + 2);
    uint4 q2 = *(const uint4*)(edges + e + 4);
    uint4 q3 = *(const uint4*)(edges + e + 6);
    GLOAD(g0, q0, x); GLOAD(g1, q0, z);
    GLOAD(g2, q1, x); GLOAD(g3, q1, z);
    GLOAD(g4, q2, x); GLOAD(g5, q2, z);
    GLOAD(g6, q3, x); GLOAD(g7, q3, z);
    CONS(g0, q0, y, accX, accY); CONS(g1, q0, w, accX, accY);
    CONS(g2, q1, y, accX, accY); CONS(g3, q1, w, accX, accY);
    CONS(g4, q2, y, accX, accY); CONS(g5, q2, w, accX, accY);
    CONS(g6, q3, y, accX, accY); CONS(g7, q3, w, accX, accY);
}

__device__ __forceinline__ void edge_one(const char* __restrict__ base, const uint2* __restrict__ edges,
                                         int e, int lane2, float& accX, float& accY) {
    uint2 ed = edges[e];
    float w = __uint_as_float(ed.y);
    float2 v = unpack_fp8x2(*(const unsigned short*)(base + ed.x + lane2));
    accX = fmaf(w, v.x, accX);
    accY = fmaf(w, v.y, accY);
}

__device__ __forceinline__ void gather2(const unsigned short* __restrict__ srcbuf,
                                        const uint2* __restrict__ edges,
                                        int e0A, int e1A, int e0B, int e1B, int lane2,
                                        float& aXA, float& aYA, float& aXB, float& aYB) {
    const char* base = (const char*)srcbuf;
    int eA = e0A, eB = e0B;
    if ((eA & 1) && eA < e1A) { edge_one(base, edges, eA, lane2, aXA, aYA); ++eA; }
    if ((eB & 1) && eB < e1B) { edge_one(base, edges, eB, lane2, aXB, aYB); ++eB; }
    while (eA + 8 <= e1A && eB + 8 <= e1B) {
        batchAB(base, edges, eA, eB, lane2, aXA, aYA, aXB, aYB);
        eA += 8; eB += 8;
    }
    while (eA + 8 <= e1A) { batch8(base, edges, eA, lane2, aXA, aYA); eA += 8; }
    while (eB + 8 <= e1B) { batch8(base, edges, eB, lane2, aXB, aYB); eB += 8; }
    for (; eA < e1A; ++eA) edge_one(base, edges, eA, lane2, aXA, aYA);
    for (; eB < e1B; ++eB) edge_one(base, edges, eB, lane2, aXB, aYB);
}

// phase2: z2 = z0_own(recomputed from fp16 h) + c*(S.z1); gate + LN; packed h update.

__device__ __forceinline__ void phase2_epi(int n, int lane, float accX, float accY,
                                           unsigned* __restrict__ hpk, unsigned short* __restrict__ z0bf8,
                                           float a, float b, float idx_, float idy_, float cx, float cy,
                                           float g, const float* __restrict__ lwr, const float* __restrict__ lbr,
                                           float a2, float b2, float idx2, float idy2, bool wz0) {
    unsigned* hp = hpk + (size_t)n * HH + lane;
    float2 hv = unpack_h2(*hp);
    float hx = hv.x, hy = hv.y;
    float xy = hx * hy;
    float z0x = (hx + DTC * (a * hx - b * xy)) * idx_;
    float z0y = (hy + DTC * (b * xy - a * hy)) * idy_;
    float z2x = fmaf(cx, accX, z0x);
    float z2y = fmaf(cy, accY, z0y);
    float nx = fmaf(g, z2x - hx, hx);
    float ny = fmaf(g, z2y - hy, hy);
    float s1 = nx + ny;
    float s2 = fmaf(nx, nx, ny * ny);
#pragma unroll
    for (int m = 1; m < 64; m <<= 1) {
        s1 += __shfl_xor(s1, m, 64);
        s2 += __shfl_xor(s2, m, 64);
    }
    float mean = s1 * (1.0f / 128.0f);
    float var = fmaf(-mean, mean, s2 * (1.0f / 128.0f));
    float rstd = rsqrtf(var + LNEPS);
    float ox = fmaf((nx - mean) * rstd, lwr[lane], lbr[lane]);
    float oy = fmaf((ny - mean) * rstd, lwr[HH + lane], lbr[HH + lane]);
    *hp = pack_h2(ox, oy);
    if (wz0) {
        float xy2 = ox * oy;
        float r2x = ox + DTC * (a2 * ox - b2 * xy2);
        float r2y = oy + DTC * (b2 * xy2 - a2 * oy);
        z0bf8[(size_t)n * HH + lane] = pack_fp8x2(r2x * idx2, r2y * idy2);
    }
}

__global__ __launch_bounds__(256) void k_phase2(unsigned* __restrict__ hpk,
                                                unsigned short* __restrict__ z0bf8,
                                                const unsigned short* __restrict__ z1bf8,
                                                const int* __restrict__ rp, const uint2* __restrict__ edges,
                                                const float* __restrict__ alpha, const float* __restrict__ beta,
                                                const float* __restrict__ dxp, const float* __restrict__ dyp,
                                                const float* __restrict__ taup,
                                                const float* __restrict__ lnw, const float* __restrict__ lnb,
                                                int l) {
    int lane = threadIdx.x & 63, wid = threadIdx.x >> 6;
    int nA = blockIdx.x * 8 + wid * 2;
    int nB = nA + 1;
    float a = alpha[l], b = beta[l], dx = dxp[l], dy = dyp[l];
    float idx_ = 1.0f / (1.0f + DTC * dx);
    float idy_ = 1.0f / (1.0f + DTC * dy);
    float cx = DTC * dx * idx_, cy = DTC * dy * idy_;
    int e0A = __builtin_amdgcn_readfirstlane(rp[nA]);
    int e1A = __builtin_amdgcn_readfirstlane(rp[nA + 1]);
    int e1B = __builtin_amdgcn_readfirstlane(rp[nA + 2]);
    float aXA = 0.f, aYA = 0.f, aXB = 0.f, aYB = 0.f;
    gather2(z1bf8, edges, e0A, e1A, e1A, e1B, lane * 2, aXA, aYA, aXB, aYB);
    int l2 = (l + 1 < NL) ? l + 1 : l;
    float a2 = alpha[l2], b2 = beta[l2];
    float idx2 = 1.0f / (1.0f + DTC * dxp[l2]);
    float idy2 = 1.0f / (1.0f + DTC * dyp[l2]);
    float g = 1.0f / (1.0f + expf(-taup[l]));
    bool wz0 = (l + 1 < NL);
    const float* lwr = lnw + (size_t)l * 128;
    const float* lbr = lnb + (size_t)l * 128;
    phase2_epi(nA, lane, aXA, aYA, hpk, z0bf8, a, b, idx_, idy_, cx, cy, g, lwr, lbr, a2, b2, idx2, idy2, wz0);
    phase2_epi(nB, lane, aXB, aYB, hpk, z0bf8, a, b, idx_, idy_, cx, cy, g, lwr, lbr, a2, b2, idx2, idy2, wz0);
}

// ---------------- output head (reads packed h, X half) ----------------

__global__ __launch_bounds__(256) void k_out(const unsigned* __restrict__ hpk, const float* __restrict__ ow,
                                             const float* __restrict__ ob, const float* __restrict__ lsp,
                                             float* __restrict__ out) {
    __shared__ float hs[64][65];
    __shared__ float ows[NCLS][65];
    __shared__ float obs[NCLS];
    int t = threadIdx.x;
    int n0 = blockIdx.x * 64;
#pragma unroll
    for (int i = 0; i < 16; ++i) {
        int idx = i * 256 + t;
        int r = idx >> 6, c = idx & 63;
        int n = n0 + r;
        hs[r][c] = (n < NN) ? unpack_h2(hpk[(size_t)n * HH + c]).x : 0.f;
    }
#pragma unroll
    for (int i = 0; i < 10; ++i) {
        int idx = i * 256 + t;
        int j = idx >> 6, c = idx & 63;
        ows[j][c] = ow[j * HH + c];
    }
    if (t < NCLS) obs[t] = ob[t];
    __syncthreads();
    float ls = lsp[0];
#pragma unroll
    for (int i = 0; i < 10; ++i) {
        int o = i * 256 + t;
        int nl = o / NCLS;
        int j = o - nl * NCLS;
        float acc = 0.f;
#pragma unroll 8
        for (int k = 0; k < HH; ++k) acc = fmaf(hs[nl][k], ows[j][k], acc);
        int n = n0 + nl;
        if (n < NN) out[(size_t)n * NCLS + j] = fmaf(ls, acc, obs[j]);
    }
}

// ---------------- launcher ----------------

extern "C" void kernel_launch(void* const* d_in, const int* in_sizes, int n_in,
                              void* d_out, int out_size, void* d_ws, size_t ws_size,
                              hipStream_t stream) {
    const float* x     = (const float*)d_in[0];
    const int*   ei    = (const int*)d_in[1];
    const float* lw    = (const float*)d_in[2];
    const float* lb    = (const float*)d_in[3];
    const float* alpha = (const float*)d_in[4];
    const float* beta  = (const float*)d_in[5];
    const float* dxp   = (const float*)d_in[6];
    const float* dyp   = (const float*)d_in[7];
    const float* taup  = (const float*)d_in[8];
    const float* lnw   = (const float*)d_in[9];
    const float* lnb   = (const float*)d_in[10];
    const float* ow    = (const float*)d_in[11];
    const float* ob    = (const float*)d_in[12];
    const float* lsp   = (const float*)d_in[13];
    float* out = (float*)d_out;

    const int* srcp = ei;
    const int* dstp = ei + NE;

    char* ws = (char*)d_ws;
    size_t o = 0;
    auto alloc = [&](size_t b) { size_t r = o; o += (b + 255) & ~(size_t)255; return r; };
    int*            row_ptr = (int*)(ws + alloc((NN + 1) * sizeof(int)));
    int*            deg     = (int*)(ws + alloc(NN * sizeof(int)));
    int*            cnt     = (int*)(ws + alloc(NN * sizeof(int)));
    float*          dinv    = (float*)(ws + alloc(NN * sizeof(float)));
    int*            bsum    = (int*)(ws + alloc(256 * sizeof(int)));
    int*            boff    = (int*)(ws + alloc(256 * sizeof(int)));
    uint2*          edges   = (uint2*)(ws + alloc((size_t)NE * sizeof(uint2)));
    unsigned*       hpk     = (unsigned*)(ws + alloc((size_t)NN * HH * sizeof(unsigned)));
    unsigned short* z0bf8   = (unsigned short*)(ws + alloc((size_t)NN * HH * sizeof(unsigned short)));
    unsigned short* z1bf8   = (unsigned short*)(ws + alloc((size_t)NN * HH * sizeof(unsigned short)));

    hipMemsetAsync(deg, 0, NN * sizeof(int), stream);
    hipMemsetAsync(cnt, 0, NN * sizeof(int), stream);

    k_deg<<<(NE + 255) / 256, 256, 0, stream>>>(dstp, deg);
    k_scan1<<<NB_SCAN, 256, 0, stream>>>(deg, row_ptr, bsum, dinv);
    k_scan2<<<1, 256, 0, stream>>>(bsum, boff);
    k_scan3<<<NB_SCAN, 256, 0, stream>>>(row_ptr, boff);
    k_scatter<<<(NE + 255) / 256, 256, 0, stream>>>(srcp, dstp, dinv, row_ptr, cnt, edges);

    k_lift<<<NN / LIFT_NPB, 256, 0, stream>>>(x, lw, lb, alpha, beta, dxp, dyp, hpk, z0bf8);

    for (int l = 0; l < NL; ++l) {
        k_phase1h<<<NN / 4, 256, 0, stream>>>(z0bf8, z1bf8, row_ptr, edges, dxp, dyp, l, 0);
        k_phase1h<<<NN / 4, 256, 0, stream>>>(z0bf8, z1bf8, row_ptr, edges, dxp, dyp, l, 1);
        k_phase2<<<NN / 8, 256, 0, stream>>>(hpk, z0bf8, z1bf8, row_ptr, edges,
                                             alpha, beta, dxp, dyp, taup, lnw, lnb, l);
    }

    k_out<<<(NN + 63) / 64, 256, 0, stream>>>(hpk, ow, ob, lsp, out);
}

// Round 15
// 983.019 us; speedup vs baseline: 1.4079x; 1.4079x over previous
//
#include <hip/hip_runtime.h>
#include <hip/hip_fp16.h>

#define NN 50000
#define NE 800000
#define CIN 128
#define HH 64
#define NCLS 40
#define NL 15
#define DTC 0.1f
#define LNEPS 1e-5f
#define NB_SCAN 196   // ceil(50000/256)

typedef float f32x2 __attribute__((ext_vector_type(2)));

// ---------------- bf16x2 / fp16x2 / fp8x2 pack-unpack ----------------

__device__ inline unsigned pack_bf2(float x, float y) {
    unsigned ux = __float_as_uint(x);
    unsigned uy = __float_as_uint(y);
    ux = (ux + 0x7fffu + ((ux >> 16) & 1u)) >> 16;   // RNE
    uy = (uy + 0x7fffu + ((uy >> 16) & 1u)) >> 16;
    return ux | (uy << 16);
}
__device__ inline float2 unpack_bf2(unsigned p) {
    float2 r;
    r.x = __uint_as_float(p << 16);
    r.y = __uint_as_float(p & 0xffff0000u);
    return r;
}
__device__ inline unsigned pack_h2(float x, float y) {
    __half2 h = __floats2half2_rn(x, y);
    return *reinterpret_cast<unsigned*>(&h);
}
__device__ inline float2 unpack_h2(unsigned p) {
    __half2 h = *reinterpret_cast<__half2*>(&p);
    return __half22float2(h);
}
__device__ inline unsigned short pack_fp8x2(float x, float y) {
    int r = __builtin_amdgcn_cvt_pk_fp8_f32(x, y, 0, false);
    return (unsigned short)(r & 0xffff);
}
__device__ inline float2 unpack_fp8x2(unsigned short p) {
    f32x2 v = __builtin_amdgcn_cvt_pk_f32_fp8((int)(unsigned)p, false);
    float2 r; r.x = v.x; r.y = v.y; return r;
}

// ---------------- degree / normalization precompute ----------------

__global__ __launch_bounds__(256) void k_deg(const int* __restrict__ dst, int* __restrict__ deg) {
    int e = blockIdx.x * 256 + threadIdx.x;
    if (e < NE) atomicAdd(&deg[dst[e]], 1);
}

__global__ __launch_bounds__(256) void k_scan1(const int* __restrict__ deg, int* __restrict__ rp,
                                               int* __restrict__ bsum, float* __restrict__ dinv) {
    int i = blockIdx.x * 256 + threadIdx.x;
    int v = (i < NN) ? deg[i] : 0;
    if (i < NN) dinv[i] = rsqrtf(fmaxf((float)v, 1.0f));
    int lane = threadIdx.x & 63, wid = threadIdx.x >> 6;
    int inc = v;
#pragma unroll
    for (int d = 1; d < 64; d <<= 1) {
        int t = __shfl_up(inc, d, 64);
        if (lane >= d) inc += t;
    }
    __shared__ int wsum[4];
    if (lane == 63) wsum[wid] = inc;
    __syncthreads();
    int woff = 0;
#pragma unroll
    for (int w = 0; w < 4; ++w)
        if (w < wid) woff += wsum[w];
    if (i < NN) rp[i] = woff + inc - v;
    if (threadIdx.x == 255) bsum[blockIdx.x] = woff + inc;
}

__global__ __launch_bounds__(256) void k_scan2(const int* __restrict__ bsum, int* __restrict__ boff) {
    int t = threadIdx.x;
    int v = (t < NB_SCAN) ? bsum[t] : 0;
    int lane = t & 63, wid = t >> 6;
    int inc = v;
#pragma unroll
    for (int d = 1; d < 64; d <<= 1) {
        int tt = __shfl_up(inc, d, 64);
        if (lane >= d) inc += tt;
    }
    __shared__ int wsum[4];
    if (lane == 63) wsum[wid] = inc;
    __syncthreads();
    int woff = 0;
#pragma unroll
    for (int w = 0; w < 4; ++w)
        if (w < wid) woff += wsum[w];
    boff[t] = woff + inc - v;
}

__global__ __launch_bounds__(256) void k_scan3(int* __restrict__ rp, const int* __restrict__ boff) {
    int i = blockIdx.x * 256 + threadIdx.x;
    if (i < NN) rp[i] += boff[i >> 8];
    else if (i == NN) rp[NN] = NE;
}

// edge record: {src*128 byte-offset into fp8 row buffers, ewt bits} -> one 8B store
__global__ __launch_bounds__(256) void k_scatter(const int* __restrict__ src, const int* __restrict__ dst,
                                                 const float* __restrict__ dinv, const int* __restrict__ rp,
                                                 int* __restrict__ cnt, uint2* __restrict__ edges) {
    int e = blockIdx.x * 256 + threadIdx.x;
    if (e >= NE) return;
    int s = src[e], d = dst[e];
    int pos = rp[d] + atomicAdd(&cnt[d], 1);
    uint2 rec;
    rec.x = (unsigned)s * 128u;           // byte offset of row s (64 ch * 2B)
    rec.y = __float_as_uint(dinv[s] * dinv[d]);
    edges[pos] = rec;
}

// ---------------- lift: h = [tanh(x @ lift_w^T + b), ones]; packed h + layer-0 z0 ----

#define LIFT_NPB 16

__global__ __launch_bounds__(256) void k_lift(const float* __restrict__ x, const float* __restrict__ lw,
                                              const float* __restrict__ lb,
                                              const float* __restrict__ alpha, const float* __restrict__ beta,
                                              const float* __restrict__ dxp, const float* __restrict__ dyp,
                                              unsigned* __restrict__ hpk, unsigned short* __restrict__ z0bf8) {
    __shared__ unsigned Wt2[CIN / 2][HH + 1];
    __shared__ float xs[LIFT_NPB][CIN];
    int t = threadIdx.x;
    for (int idx = t; idx < (CIN / 2) * HH; idx += 256) {
        int c = idx & 63, kk = idx >> 6;
        Wt2[kk][c] = pack_bf2(lw[c * CIN + 2 * kk], lw[c * CIN + 2 * kk + 1]);
    }
    int n0 = blockIdx.x * LIFT_NPB;
#pragma unroll
    for (int i = 0; i < LIFT_NPB * CIN / 256; ++i) {
        int idx = i * 256 + t;
        int r = idx >> 7, c = idx & 127;
        xs[r][c] = x[(size_t)(n0 + r) * CIN + c];
    }
    __syncthreads();
    int lane = t & 63, wid = t >> 6;
    float bias = lb[lane];
    float a = alpha[0], b = beta[0];
    float idx0 = 1.0f / (1.0f + DTC * dxp[0]);
    float idy0 = 1.0f / (1.0f + DTC * dyp[0]);
    const float2* x0 = (const float2*)&xs[wid * 4 + 0][0];
    const float2* x1 = (const float2*)&xs[wid * 4 + 1][0];
    const float2* x2 = (const float2*)&xs[wid * 4 + 2][0];
    const float2* x3 = (const float2*)&xs[wid * 4 + 3][0];
    float ac0 = 0.f, ac1 = 0.f, ac2 = 0.f, ac3 = 0.f;
#pragma unroll 8
    for (int kk = 0; kk < CIN / 2; ++kk) {
        float2 wv = unpack_bf2(Wt2[kk][lane]);
        float2 v0 = x0[kk], v1 = x1[kk], v2 = x2[kk], v3 = x3[kk];
        ac0 = fmaf(v0.y, wv.y, fmaf(v0.x, wv.x, ac0));
        ac1 = fmaf(v1.y, wv.y, fmaf(v1.x, wv.x, ac1));
        ac2 = fmaf(v2.y, wv.y, fmaf(v2.x, wv.x, ac2));
        ac3 = fmaf(v3.y, wv.y, fmaf(v3.x, wv.x, ac3));
    }
#pragma unroll
    for (int i = 0; i < 4; ++i) {
        float acc = i == 0 ? ac0 : i == 1 ? ac1 : i == 2 ? ac2 : ac3;
        float hx = tanhf(bias + acc);
        int n = n0 + wid * 4 + i;
        hpk[(size_t)n * HH + lane] = pack_h2(hx, 1.0f);
        float rx = hx + DTC * (a * hx - b * hx);
        float ry = 1.0f + DTC * (b * hx - a);
        z0bf8[(size_t)n * HH + lane] = pack_fp8x2(rx * idx0, ry * idy0);
    }
}

// ---------------- gather core ----------------
// Edge-range bounds are wave-uniform SGPRs (readfirstlane'd) so uint4 edge
// record loads are scalar (SMEM). batchAB issues ALL 16 gathers (two streams)
// before consuming any -> ~16 outstanding VMEM loads per wave.

#define GLOAD(g, q, comp) unsigned short g = *(const unsigned short*)(base + q.comp + lane2)
#define CONS(g, q, wcomp, aX, aY)                                      \
    do {                                                               \
        float2 v = unpack_fp8x2(g);                                    \
        float w = __uint_as_float(q.wcomp);                            \
        aX = fmaf(w, v.x, aX);                                         \
        aY = fmaf(w, v.y, aY);                                         \
    } while (0)

__device__ __forceinline__ void batchAB(const char* __restrict__ base, const uint2* __restrict__ edges,
                                        int eA, int eB, int lane2,
                                        float& aXA, float& aYA, float& aXB, float& aYB) {
    uint4 qa0 = *(const uint4*)(edges + eA);
    uint4 qa1 = *(const uint4*)(edges + eA + 2);
    uint4 qa2 = *(const uint4*)(edges + eA + 4);
    uint4 qa3 = *(const uint4*)(edges + eA + 6);
    uint4 qb0 = *(const uint4*)(edges + eB);
    uint4 qb1 = *(const uint4*)(edges + eB + 2);
    uint4 qb2 = *(const uint4*)(edges + eB + 4);
    uint4 qb3 = *(const uint4*)(edges + eB + 6);
    GLOAD(ga0, qa0, x); GLOAD(ga1, qa0, z);
    GLOAD(ga2, qa1, x); GLOAD(ga3, qa1, z);
    GLOAD(ga4, qa2, x); GLOAD(ga5, qa2, z);
    GLOAD(ga6, qa3, x); GLOAD(ga7, qa3, z);
    GLOAD(gb0, qb0, x); GLOAD(gb1, qb0, z);
    GLOAD(gb2, qb1, x); GLOAD(gb3, qb1, z);
    GLOAD(gb4, qb2, x); GLOAD(gb5, qb2, z);
    GLOAD(gb6, qb3, x); GLOAD(gb7, qb3, z);
    CONS(ga0, qa0, y, aXA, aYA); CONS(ga1, qa0, w, aXA, aYA);
    CONS(ga2, qa1, y, aXA, aYA); CONS(ga3, qa1, w, aXA, aYA);
    CONS(ga4, qa2, y, aXA, aYA); CONS(ga5, qa2, w, aXA, aYA);
    CONS(ga6, qa3, y, aXA, aYA); CONS(ga7, qa3, w, aXA, aYA);
    CONS(gb0, qb0, y, aXB, aYB); CONS(gb1, qb0, w, aXB, aYB);
    CONS(gb2, qb1, y, aXB, aYB); CONS(gb3, qb1, w, aXB, aYB);
    CONS(gb4, qb2, y, aXB, aYB); CONS(gb5, qb2, w, aXB, aYB);
    CONS(gb6, qb3, y, aXB, aYB); CONS(gb7, qb3, w, aXB, aYB);
}

__device__ __forceinline__ void batch8(const char* __restrict__ base, const uint2* __restrict__ edges,
                                       int e, int lane2, float& accX, float& accY) {
    uint4 q0 = *(const uint4*)(edges + e);
    uint4 q1 = *(const uint4*)(edges + e + 2);
    uint4 q2 = *(const uint4*)(edges + e + 4);
    uint4 q3 = *(const uint4*)(edges + e + 6);
    GLOAD(g0, q0, x); GLOAD(g1, q0, z);
    GLOAD(g2, q1, x); GLOAD(g3, q1, z);
    GLOAD(g4, q2, x); GLOAD(g5, q2, z);
    GLOAD(g6, q3, x); GLOAD(g7, q3, z);
    CONS(g0, q0, y, accX, accY); CONS(g1, q0, w, accX, accY);
    CONS(g2, q1, y, accX, accY); CONS(g3, q1, w, accX, accY);
    CONS(g4, q2, y, accX, accY); CONS(g5, q2, w, accX, accY);
    CONS(g6, q3, y, accX, accY); CONS(g7, q3, w, accX, accY);
}

__device__ __forceinline__ void edge_one(const char* __restrict__ base, const uint2* __restrict__ edges,
                                         int e, int lane2, float& accX, float& accY) {
    uint2 ed = edges[e];
    float w = __uint_as_float(ed.y);
    float2 v = unpack_fp8x2(*(const unsigned short*)(base + ed.x + lane2));
    accX = fmaf(w, v.x, accX);
    accY = fmaf(w, v.y, accY);
}

__device__ __forceinline__ void gather2(const unsigned short* __restrict__ srcbuf,
                                        const uint2* __restrict__ edges,
                                        int e0A, int e1A, int e0B, int e1B, int lane2,
                                        float& aXA, float& aYA, float& aXB, float& aYB) {
    const char* base = (const char*)srcbuf;
    int eA = e0A, eB = e0B;
    if ((eA & 1) && eA < e1A) { edge_one(base, edges, eA, lane2, aXA, aYA); ++eA; }
    if ((eB & 1) && eB < e1B) { edge_one(base, edges, eB, lane2, aXB, aYB); ++eB; }
    while (eA + 8 <= e1A && eB + 8 <= e1B) {
        batchAB(base, edges, eA, eB, lane2, aXA, aYA, aXB, aYB);
        eA += 8; eB += 8;
    }
    while (eA + 8 <= e1A) { batch8(base, edges, eA, lane2, aXA, aYA); eA += 8; }
    while (eB + 8 <= e1B) { batch8(base, edges, eB, lane2, aXB, aYB); eB += 8; }
    for (; eA < e1A; ++eA) edge_one(base, edges, eA, lane2, aXA, aYA);
    for (; eB < e1B; ++eB) edge_one(base, edges, eB, lane2, aXB, aYB);
}

// ---------------- phase kernels (2 nodes per wave) ----------------
// phase1: z1 = z0_own(fp8) + c*(S.z0) — no h access at all.

__global__ __launch_bounds__(256) void k_phase1(const unsigned short* __restrict__ z0bf8,
                                                unsigned short* __restrict__ z1bf8,
                                                const int* __restrict__ rp, const uint2* __restrict__ edges,
                                                const float* __restrict__ dxp, const float* __restrict__ dyp,
                                                int l) {
    int lane = threadIdx.x & 63, wid = threadIdx.x >> 6;
    int nA = blockIdx.x * 8 + wid * 2;       // grid = NN/8 = 6250
    int nB = nA + 1;
    float dx = dxp[l], dy = dyp[l];
    float cx = DTC * dx / (1.0f + DTC * dx);
    float cy = DTC * dy / (1.0f + DTC * dy);
    int e0A = __builtin_amdgcn_readfirstlane(rp[nA]);
    int e1A = __builtin_amdgcn_readfirstlane(rp[nA + 1]);
    int e1B = __builtin_amdgcn_readfirstlane(rp[nA + 2]);
    float aXA = 0.f, aYA = 0.f, aXB = 0.f, aYB = 0.f;
    gather2(z0bf8, edges, e0A, e1A, e1A, e1B, lane * 2, aXA, aYA, aXB, aYB);
    float2 zA = unpack_fp8x2(z0bf8[(size_t)nA * HH + lane]);
    float2 zB = unpack_fp8x2(z0bf8[(size_t)nB * HH + lane]);
    z1bf8[(size_t)nA * HH + lane] = pack_fp8x2(fmaf(cx, aXA, zA.x), fmaf(cy, aYA, zA.y));
    z1bf8[(size_t)nB * HH + lane] = pack_fp8x2(fmaf(cx, aXB, zB.x), fmaf(cy, aYB, zB.y));
}

// phase2: z2 = z0_own(recomputed from fp16 h) + c*(S.z1); gate + LN; packed h update.

__device__ __forceinline__ void phase2_epi(int n, int lane, float accX, float accY,
                                           unsigned* __restrict__ hpk, unsigned short* __restrict__ z0bf8,
                                           float a, float b, float idx_, float idy_, float cx, float cy,
                                           float g, const float* __restrict__ lwr, const float* __restrict__ lbr,
                                           float a2, float b2, float idx2, float idy2, bool wz0) {
    unsigned* hp = hpk + (size_t)n * HH + lane;
    float2 hv = unpack_h2(*hp);
    float hx = hv.x, hy = hv.y;
    float xy = hx * hy;
    float z0x = (hx + DTC * (a * hx - b * xy)) * idx_;
    float z0y = (hy + DTC * (b * xy - a * hy)) * idy_;
    float z2x = fmaf(cx, accX, z0x);
    float z2y = fmaf(cy, accY, z0y);
    float nx = fmaf(g, z2x - hx, hx);
    float ny = fmaf(g, z2y - hy, hy);
    float s1 = nx + ny;
    float s2 = fmaf(nx, nx, ny * ny);
#pragma unroll
    for (int m = 1; m < 64; m <<= 1) {
        s1 += __shfl_xor(s1, m, 64);
        s2 += __shfl_xor(s2, m, 64);
    }
    float mean = s1 * (1.0f / 128.0f);
    float var = fmaf(-mean, mean, s2 * (1.0f / 128.0f));
    float rstd = rsqrtf(var + LNEPS);
    float ox = fmaf((nx - mean) * rstd, lwr[lane], lbr[lane]);
    float oy = fmaf((ny - mean) * rstd, lwr[HH + lane], lbr[HH + lane]);
    *hp = pack_h2(ox, oy);
    if (wz0) {
        float xy2 = ox * oy;
        float r2x = ox + DTC * (a2 * ox - b2 * xy2);
        float r2y = oy + DTC * (b2 * xy2 - a2 * oy);
        z0bf8[(size_t)n * HH + lane] = pack_fp8x2(r2x * idx2, r2y * idy2);
    }
}

__global__ __launch_bounds__(256) void k_phase2(unsigned* __restrict__ hpk,
                                                unsigned short* __restrict__ z0bf8,
                                                const unsigned short* __restrict__ z1bf8,
                                                const int* __restrict__ rp, const uint2* __restrict__ edges,
                                                const float* __restrict__ alpha, const float* __restrict__ beta,
                                                const float* __restrict__ dxp, const float* __restrict__ dyp,
                                                const float* __restrict__ taup,
                                                const float* __restrict__ lnw, const float* __restrict__ lnb,
                                                int l) {
    int lane = threadIdx.x & 63, wid = threadIdx.x >> 6;
    int nA = blockIdx.x * 8 + wid * 2;
    int nB = nA + 1;
    float a = alpha[l], b = beta[l], dx = dxp[l], dy = dyp[l];
    float idx_ = 1.0f / (1.0f + DTC * dx);
    float idy_ = 1.0f / (1.0f + DTC * dy);
    float cx = DTC * dx * idx_, cy = DTC * dy * idy_;
    int e0A = __builtin_amdgcn_readfirstlane(rp[nA]);
    int e1A = __builtin_amdgcn_readfirstlane(rp[nA + 1]);
    int e1B = __builtin_amdgcn_readfirstlane(rp[nA + 2]);
    float aXA = 0.f, aYA = 0.f, aXB = 0.f, aYB = 0.f;
    gather2(z1bf8, edges, e0A, e1A, e1A, e1B, lane * 2, aXA, aYA, aXB, aYB);
    int l2 = (l + 1 < NL) ? l + 1 : l;
    float a2 = alpha[l2], b2 = beta[l2];
    float idx2 = 1.0f / (1.0f + DTC * dxp[l2]);
    float idy2 = 1.0f / (1.0f + DTC * dyp[l2]);
    float g = 1.0f / (1.0f + expf(-taup[l]));
    bool wz0 = (l + 1 < NL);
    const float* lwr = lnw + (size_t)l * 128;
    const float* lbr = lnb + (size_t)l * 128;
    phase2_epi(nA, lane, aXA, aYA, hpk, z0bf8, a, b, idx_, idy_, cx, cy, g, lwr, lbr, a2, b2, idx2, idy2, wz0);
    phase2_epi(nB, lane, aXB, aYB, hpk, z0bf8, a, b, idx_, idy_, cx, cy, g, lwr, lbr, a2, b2, idx2, idy2, wz0);
}

// ---------------- output head (reads packed h, X half) ----------------

__global__ __launch_bounds__(256) void k_out(const unsigned* __restrict__ hpk, const float* __restrict__ ow,
                                             const float* __restrict__ ob, const float* __restrict__ lsp,
                                             float* __restrict__ out) {
    __shared__ float hs[64][65];
    __shared__ float ows[NCLS][65];
    __shared__ float obs[NCLS];
    int t = threadIdx.x;
    int n0 = blockIdx.x * 64;
#pragma unroll
    for (int i = 0; i < 16; ++i) {
        int idx = i * 256 + t;
        int r = idx >> 6, c = idx & 63;
        int n = n0 + r;
        hs[r][c] = (n < NN) ? unpack_h2(hpk[(size_t)n * HH + c]).x : 0.f;
    }
#pragma unroll
    for (int i = 0; i < 10; ++i) {
        int idx = i * 256 + t;
        int j = idx >> 6, c = idx & 63;
        ows[j][c] = ow[j * HH + c];
    }
    if (t < NCLS) obs[t] = ob[t];
    __syncthreads();
    float ls = lsp[0];
#pragma unroll
    for (int i = 0; i < 10; ++i) {
        int o = i * 256 + t;
        int nl = o / NCLS;
        int j = o - nl * NCLS;
        float acc = 0.f;
#pragma unroll 8
        for (int k = 0; k < HH; ++k) acc = fmaf(hs[nl][k], ows[j][k], acc);
        int n = n0 + nl;
        if (n < NN) out[(size_t)n * NCLS + j] = fmaf(ls, acc, obs[j]);
    }
}

// ---------------- launcher ----------------

extern "C" void kernel_launch(void* const* d_in, const int* in_sizes, int n_in,
                              void* d_out, int out_size, void* d_ws, size_t ws_size,
                              hipStream_t stream) {
    const float* x     = (const float*)d_in[0];
    const int*   ei    = (const int*)d_in[1];
    const float* lw    = (const float*)d_in[2];
    const float* lb    = (const float*)d_in[3];
    const float* alpha = (const float*)d_in[4];
    const float* beta  = (const float*)d_in[5];
    const float* dxp   = (const float*)d_in[6];
    const float* dyp   = (const float*)d_in[7];
    const float* taup  = (const float*)d_in[8];
    const float* lnw   = (const float*)d_in[9];
    const float* lnb   = (const float*)d_in[10];
    const float* ow    = (const float*)d_in[11];
    const float* ob    = (const float*)d_in[12];
    const float* lsp   = (const float*)d_in[13];
    float* out = (float*)d_out;

    const int* srcp = ei;
    const int* dstp = ei + NE;

    char* ws = (char*)d_ws;
    size_t o = 0;
    auto alloc = [&](size_t b) { size_t r = o; o += (b + 255) & ~(size_t)255; return r; };
    int*            row_ptr = (int*)(ws + alloc((NN + 1) * sizeof(int)));
    int*            deg     = (int*)(ws + alloc(NN * sizeof(int)));
    int*            cnt     = (int*)(ws + alloc(NN * sizeof(int)));
    float*          dinv    = (float*)(ws + alloc(NN * sizeof(float)));
    int*            bsum    = (int*)(ws + alloc(256 * sizeof(int)));
    int*            boff    = (int*)(ws + alloc(256 * sizeof(int)));
    uint2*          edges   = (uint2*)(ws + alloc((size_t)NE * sizeof(uint2)));
    unsigned*       hpk     = (unsigned*)(ws + alloc((size_t)NN * HH * sizeof(unsigned)));
    unsigned short* z0bf8   = (unsigned short*)(ws + alloc((size_t)NN * HH * sizeof(unsigned short)));
    unsigned short* z1bf8   = (unsigned short*)(ws + alloc((size_t)NN * HH * sizeof(unsigned short)));

    hipMemsetAsync(deg, 0, NN * sizeof(int), stream);
    hipMemsetAsync(cnt, 0, NN * sizeof(int), stream);

    k_deg<<<(NE + 255) / 256, 256, 0, stream>>>(dstp, deg);
    k_scan1<<<NB_SCAN, 256, 0, stream>>>(deg, row_ptr, bsum, dinv);
    k_scan2<<<1, 256, 0, stream>>>(bsum, boff);
    k_scan3<<<NB_SCAN, 256, 0, stream>>>(row_ptr, boff);
    k_scatter<<<(NE + 255) / 256, 256, 0, stream>>>(srcp, dstp, dinv, row_ptr, cnt, edges);

    k_lift<<<NN / LIFT_NPB, 256, 0, stream>>>(x, lw, lb, alpha, beta, dxp, dyp, hpk, z0bf8);

    for (int l = 0; l < NL; ++l) {
        k_phase1<<<NN / 8, 256, 0, stream>>>(z0bf8, z1bf8, row_ptr, edges, dxp, dyp, l);
        k_phase2<<<NN / 8, 256, 0, stream>>>(hpk, z0bf8, z1bf8, row_ptr, edges,
                                             alpha, beta, dxp, dyp, taup, lnw, lnb, l);
    }

    k_out<<<(NN + 63) / 64, 256, 0, stream>>>(hpk, ow, ob, lsp, out);
}